// Round 10
// baseline (588.399 us; speedup 1.0000x reference)
//
#include <hip/hip_runtime.h>

#define N_NODES 100000
#define N_EDGES 1600000
#define IN_CH   64
#define HID_CH  64
#define OUT_CH  128

typedef __attribute__((ext_vector_type(8))) __bf16    bf16x8;
typedef __attribute__((ext_vector_type(4))) float     f32x4;
typedef __attribute__((ext_vector_type(2))) _Float16  f16x2;
typedef __attribute__((ext_vector_type(8))) _Float16  f16x8;

// ---- workspace byte offsets (total ~54.6 MB) ----
#define OFF_HSUM   0            // 100000*64*2  = 12,800,000 (f16 pairs, natural order)
#define OFF_Z      12800000     // 100000*128*2 = 25,600,000 (f16: [0:64]=dst-half, [64:128]=src-half)
#define OFF_CREC   38400000     // 980000*16    = 15,680,000 (compacted edge records)
#define OFF_CNT    54080000     // 100000*4
#define OFF_NTYPE  54480000     // 100000*1
#define OFF_CURSOR 54580000     // 4 (16B-aligned)
#define CREC_CAP   980000       // expected 960K (mask rate exactly 0.6), +32 sigma

__device__ __forceinline__ unsigned short f2bf(float f) {
    union { float f; unsigned int i; } c;
    c.f = f;
    unsigned int u = c.i;
    unsigned int r = (u + 0x7FFFu + ((u >> 16) & 1u)) >> 16;   // RNE
    return (unsigned short)r;
}

// packed fp16 atomic add (global_atomic_pk_add_f16, gfx90a+)
__device__ __forceinline__ void atomic_pk_add_f16(unsigned int* addr, f16x2 val) {
    typedef __attribute__((address_space(1))) f16x2 gf16x2;
    __builtin_amdgcn_global_atomic_fadd_v2f16((gf16x2*)(void*)addr, val);
}

// prep0: zero hsum + cnt + cursor (pure memset).
__global__ void gnn_prep0(uint4* __restrict__ hz,      // hsum as uint4 (800k)
                          float4* __restrict__ cz,     // cnt as float4 (25k)
                          unsigned* __restrict__ cursor) {
    int i = blockIdx.x * blockDim.x + threadIdx.x;
    if (i < 800000) {
        hz[i] = (uint4){0u, 0u, 0u, 0u};
    } else if (i < 825000) {
        cz[i - 800000] = (float4){0.f, 0.f, 0.f, 0.f};
    } else if (i == 825000) {
        *cursor = 0u;
    }
}

// zgemm: z[n][j] = sum_k x[n][k]*Bc[k][j]; Bc[k][j<64]=W1[k][j] (dst half),
// Bc[k][j>=64]=W1[64+k][j-64] (src half). Reads x f32 directly (convert
// in-reg -> no xb intermediate); writes ntype byte table as a side effect
// (q==0 lanes hold x[node][0]).
__global__ __launch_bounds__(256, 4) void gnn_zgemm(
    const float* __restrict__ x,     // [N_NODES][64] f32
    const float* __restrict__ W1,    // [131][64]
    _Float16*    __restrict__ z,     // [N_NODES][128]
    unsigned char* __restrict__ ntype)
{
    __shared__ __align__(16) unsigned short BT[128][72];  // BT[j][k]=Bc[k][j]

    const int tid  = threadIdx.x;
    const int wave = tid >> 6;
    const int lane = tid & 63;
    const int q    = lane >> 4;
    const int m16  = lane & 15;

    for (int idx = tid; idx < 64 * 128; idx += 256) {
        int k = idx >> 7, j = idx & 127;
        BT[j][k] = f2bf(W1[(k + ((j >= 64) ? 64 : 0)) * 64 + (j & 63)]);
    }
    __syncthreads();

    const int nodeBase = (blockIdx.x * 4 + wave) * 32;
    if (nodeBase >= N_NODES) return;

    f32x4 acc[2][8];
#pragma unroll
    for (int mt = 0; mt < 2; ++mt)
#pragma unroll
        for (int nt = 0; nt < 8; ++nt)
            acc[mt][nt] = (f32x4){0.0f, 0.0f, 0.0f, 0.0f};

#pragma unroll
    for (int kc = 0; kc < 2; ++kc) {
        bf16x8 af[2];
#pragma unroll
        for (int mt = 0; mt < 2; ++mt) {
            int node = nodeBase + mt * 16 + m16;
            if (node >= N_NODES) node = N_NODES - 1;   // clamp; rows unused
            const float4* xr = reinterpret_cast<const float4*>(
                x + (size_t)node * 64 + kc * 32 + q * 8);
            float4 xa = xr[0], xb = xr[1];
            union { bf16x8 v; unsigned short u[8]; } rr;
            rr.u[0] = f2bf(xa.x); rr.u[1] = f2bf(xa.y);
            rr.u[2] = f2bf(xa.z); rr.u[3] = f2bf(xa.w);
            rr.u[4] = f2bf(xb.x); rr.u[5] = f2bf(xb.y);
            rr.u[6] = f2bf(xb.z); rr.u[7] = f2bf(xb.w);
            af[mt] = rr.v;
            if (kc == 0 && q == 0)   // xa.x = x[node][0] = node type
                ntype[node] = (xa.x == 0.0f) ? 0 : ((xa.x == 1.0f) ? 1 : 2);
        }
#pragma unroll
        for (int nt = 0; nt < 8; ++nt) {
            bf16x8 bfr = *reinterpret_cast<const bf16x8*>(
                &BT[nt * 16 + m16][kc * 32 + q * 8]);
            acc[0][nt] = __builtin_amdgcn_mfma_f32_16x16x32_bf16(af[0], bfr, acc[0][nt], 0, 0, 0);
            acc[1][nt] = __builtin_amdgcn_mfma_f32_16x16x32_bf16(af[1], bfr, acc[1][nt], 0, 0, 0);
        }
    }

    // C-layout: row = q*4+r, col = nt*16+m16
#pragma unroll
    for (int mt = 0; mt < 2; ++mt) {
#pragma unroll
        for (int nt = 0; nt < 8; ++nt) {
            int col = nt * 16 + m16;
#pragma unroll
            for (int r = 0; r < 4; ++r) {
                int n = nodeBase + mt * 16 + q * 4 + r;
                if (n < N_NODES)
                    z[(size_t)n * 128 + col] = (_Float16)acc[mt][nt][r];
            }
        }
    }
}

// compact: masked-in edges -> unordered record array {s,d,a0,a1|a2 f16} via
// wave-ballot + one cursor atomic per wave. Also bumps cnt[d]. Removes the
// per-edge mask/ntype dependent load from the hot edge loop and shrinks its
// streaming input 32MB -> 15.4MB sequential.
__global__ void gnn_compact(const int* __restrict__ eidx,
                            const float* __restrict__ ea,
                            const unsigned char* __restrict__ ntype,
                            unsigned* __restrict__ cursor,
                            float4* __restrict__ crec,
                            float* __restrict__ cnt) {
    int e = blockIdx.x * 256 + threadIdx.x;   // N_EDGES % 256 == 0: no stragglers
    int lane = threadIdx.x & 63;

    int s = eidx[e];
    float a0 = ea[e * 3];
    int ntc = ntype[s];
    bool mk = (ntc == 0) ? (a0 < 0.5f) : ((ntc == 1) ? (a0 < 0.3f) : true);

    unsigned long long bal = __ballot(mk);
    int nact = __popcll(bal);
    if (nact == 0) return;                     // wave-uniform
    int prefix = __popcll(bal & ((1ULL << lane) - 1ULL));
    int leader = __ffsll((long long)bal) - 1;
    unsigned base = 0;
    if (lane == leader) base = atomicAdd(cursor, (unsigned)nact);
    base = __shfl(base, leader);

    if (mk) {
        unsigned pos = base + (unsigned)prefix;
        if (pos < CREC_CAP) {
            int d = eidx[N_EDGES + e];
            union { f16x2 v; float f; } pk;
            pk.v = (f16x2){(_Float16)ea[e * 3 + 1], (_Float16)ea[e * 3 + 2]};
            float4 rec;
            rec.x = __int_as_float(s);
            rec.y = __int_as_float(d);
            rec.z = a0;
            rec.w = pk.f;
            crec[pos] = rec;
            unsafeAtomicAdd(&cnt[d], 1.0f);
        }
    }
}

// edge_quad2: quad-per-edge (r9's proven coalescing geometry), BATCHED x4.
// r9 showed occupancy 87% + correct traffic but dur still 175us, VALUBusy 20%:
// suspect vmcnt FIFO serialization — each iteration's gather-wait also waits
// for the previous iteration's fire-and-forget atomics (issue-ordered vmcnt),
// and at VGPR=24 the compiler couldn't pipeline. This kernel processes 4
// records per quad per iteration in phases: 4 record loads -> 16 z-gathers ->
// compute -> 8 atomics. Waits-per-edge /4, in-flight loads x4 (VGPR ~80).
// No LDS, no barriers, no mask work (pre-compacted input).
__global__ __launch_bounds__(256, 4) void gnn_edge_quad2(
    const float4*   __restrict__ crec,   // compacted records
    const unsigned* __restrict__ ncomp,  // record count
    const _Float16* __restrict__ z,      // [N_NODES][128]
    const float*    __restrict__ W1,     // [131][64]
    const float*    __restrict__ b1,     // [64]
    unsigned int*   __restrict__ hsum)   // [N_NODES][32] f16 pairs (natural)
{
    const int tid = threadIdx.x;
    const int m16 = tid & 15;
    const int c0  = 2 * m16;

    // per-lane weight tail in registers: channels c0, c0+1, c0+32, c0+33
    const float wx0 = W1[128 * 64 + c0],      wx1 = W1[128 * 64 + c0 + 1];
    const float wx2 = W1[128 * 64 + c0 + 32], wx3 = W1[128 * 64 + c0 + 33];
    const float wy0 = W1[129 * 64 + c0],      wy1 = W1[129 * 64 + c0 + 1];
    const float wy2 = W1[129 * 64 + c0 + 32], wy3 = W1[129 * 64 + c0 + 33];
    const float wz0 = W1[130 * 64 + c0],      wz1 = W1[130 * 64 + c0 + 1];
    const float wz2 = W1[130 * 64 + c0 + 32], wz3 = W1[130 * 64 + c0 + 33];
    const float bb0 = b1[c0],                 bb1 = b1[c0 + 1];
    const float bb2 = b1[c0 + 32],            bb3 = b1[c0 + 33];

    const int n  = (int)*ncomp;
    const int gq = (blockIdx.x * 256 + tid) >> 4;   // global quad id
    const int nq = (gridDim.x * 256) >> 4;

    for (int i0 = gq * 4; i0 < n; i0 += nq * 4) {
        // ---- phase 1: up to 4 record loads (quad-uniform addresses) ----
        float4 rec[4];
        bool   v[4];
        int    s[4], d[4];
#pragma unroll
        for (int k = 0; k < 4; ++k) {
            int i = i0 + k;
            v[k] = (i < n);
            rec[k] = v[k] ? crec[i] : (float4){0.f, 0.f, 0.f, 0.f};
            s[k] = __float_as_int(rec[k].x);   // 0 when invalid -> safe gather
            d[k] = __float_as_int(rec[k].y);
        }

        // ---- phase 2: 16 independent z-gathers (64B-contiguous per quad) ----
        f16x2 zd01[4], zd23[4], zs01[4], zs23[4];
#pragma unroll
        for (int k = 0; k < 4; ++k) {
            const _Float16* zd = z + (size_t)d[k] * 128;        // dst half
            const _Float16* zs = z + (size_t)s[k] * 128 + 64;   // src half
            zd01[k] = *reinterpret_cast<const f16x2*>(zd + c0);
            zd23[k] = *reinterpret_cast<const f16x2*>(zd + c0 + 32);
            zs01[k] = *reinterpret_cast<const f16x2*>(zs + c0);
            zs23[k] = *reinterpret_cast<const f16x2*>(zs + c0 + 32);
        }

        // ---- phase 3+4: compute + coalesced packed-f16 atomics ----
#pragma unroll
        for (int k = 0; k < 4; ++k) {
            if (!v[k]) continue;               // tail only
            float a0 = rec[k].z;
            union { float f; f16x2 v2; } pk; pk.f = rec[k].w;
            float a1 = (float)pk.v2[0];
            float a2 = (float)pk.v2[1];

            float h0 = (float)zd01[k][0] + (float)zs01[k][0] + bb0 + a0 * wx0 + a1 * wy0 + a2 * wz0;
            float h1 = (float)zd01[k][1] + (float)zs01[k][1] + bb1 + a0 * wx1 + a1 * wy1 + a2 * wz1;
            float h2 = (float)zd23[k][0] + (float)zs23[k][0] + bb2 + a0 * wx2 + a1 * wy2 + a2 * wz2;
            float h3 = (float)zd23[k][1] + (float)zs23[k][1] + bb3 + a0 * wx3 + a1 * wy3 + a2 * wz3;
            h0 = h0 > 0.f ? h0 : 0.f;
            h1 = h1 > 0.f ? h1 : 0.f;
            h2 = h2 > 0.f ? h2 : 0.f;
            h3 = h3 > 0.f ? h3 : 0.f;

            unsigned int* hb = hsum + (size_t)d[k] * 32;
            if (h0 + h1 > 0.f) {               // quad covers dwords 0..15
                f16x2 p = {(_Float16)h0, (_Float16)h1};
                atomic_pk_add_f16(hb + m16, p);
            }
            if (h2 + h3 > 0.f) {               // quad covers dwords 16..31
                f16x2 p = {(_Float16)h2, (_Float16)h3};
                atomic_pk_add_f16(hb + 16 + m16, p);
            }
        }
    }
}

// Node kernel (MFMA): out[n] = relu(hsum[n] @ W2 + cnt[n]*b2). (r9-verified)
__global__ __launch_bounds__(256, 4) void gnn_node_out(
    const _Float16* __restrict__ hsum,  // [N_NODES][64] f16, natural order
    const float*    __restrict__ cnt,   // [N_NODES]
    const float*    __restrict__ W2,    // [64][128]
    const float*    __restrict__ b2,    // [128]
    float*          __restrict__ out)   // [N_NODES][128]
{
    __shared__ __align__(16) unsigned short W2T[128][72];  // W2T[n][k]=W2[k][n]
    __shared__ float b2s[128];

    const int tid  = threadIdx.x;
    const int wave = tid >> 6;
    const int lane = tid & 63;
    const int q    = lane >> 4;
    const int m16  = lane & 15;

    const int nodeBase = (blockIdx.x * 4 + wave) * 32;

    // prefetch this wave's hsum rows + cnt before LDS staging (hide HBM latency)
    f16x8 hpre[2][2];
    float cc[2][4];
#pragma unroll
    for (int kc = 0; kc < 2; ++kc)
#pragma unroll
        for (int mt = 0; mt < 2; ++mt) {
            int node = nodeBase + mt * 16 + m16;
            if (node >= N_NODES) node = N_NODES - 1;
            hpre[kc][mt] = *reinterpret_cast<const f16x8*>(
                hsum + (size_t)node * HID_CH + kc * 32 + q * 8);
        }
#pragma unroll
    for (int mt = 0; mt < 2; ++mt)
#pragma unroll
        for (int r = 0; r < 4; ++r) {
            int n = nodeBase + mt * 16 + q * 4 + r;
            cc[mt][r] = (n < N_NODES) ? cnt[n] : 0.0f;
        }

    for (int idx = tid; idx < 64 * 128; idx += 256) {
        int k = idx >> 7, n = idx & 127;
        W2T[n][k] = f2bf(W2[k * 128 + n]);
    }
    if (tid < 128) b2s[tid] = b2[tid];
    __syncthreads();

    if (nodeBase >= N_NODES) return;

    f32x4 acc[2][8];
#pragma unroll
    for (int mt = 0; mt < 2; ++mt)
#pragma unroll
        for (int nt = 0; nt < 8; ++nt)
            acc[mt][nt] = (f32x4){0.0f, 0.0f, 0.0f, 0.0f};

#pragma unroll
    for (int kc = 0; kc < 2; ++kc) {
        bf16x8 af[2];
#pragma unroll
        for (int mt = 0; mt < 2; ++mt) {
            union { bf16x8 v; unsigned short u[8]; } rr;
#pragma unroll
            for (int j = 0; j < 8; ++j) rr.u[j] = f2bf((float)hpre[kc][mt][j]);
            af[mt] = rr.v;
        }
#pragma unroll
        for (int nt = 0; nt < 8; ++nt) {
            bf16x8 bfr = *reinterpret_cast<const bf16x8*>(
                &W2T[nt * 16 + m16][kc * 32 + q * 8]);
            acc[0][nt] = __builtin_amdgcn_mfma_f32_16x16x32_bf16(af[0], bfr, acc[0][nt], 0, 0, 0);
            acc[1][nt] = __builtin_amdgcn_mfma_f32_16x16x32_bf16(af[1], bfr, acc[1][nt], 0, 0, 0);
        }
    }

#pragma unroll
    for (int mt = 0; mt < 2; ++mt) {
        int nn[4];
#pragma unroll
        for (int r = 0; r < 4; ++r)
            nn[r] = nodeBase + mt * 16 + q * 4 + r;
#pragma unroll
        for (int nt = 0; nt < 8; ++nt) {
            int col = nt * 16 + m16;
            float bb = b2s[col];
#pragma unroll
            for (int r = 0; r < 4; ++r) {
                if (nn[r] < N_NODES) {
                    float v = acc[mt][nt][r] + cc[mt][r] * bb;
                    out[(size_t)nn[r] * OUT_CH + col] = v > 0.0f ? v : 0.0f;
                }
            }
        }
    }
}

extern "C" void kernel_launch(void* const* d_in, const int* in_sizes, int n_in,
                              void* d_out, int out_size, void* d_ws, size_t ws_size,
                              hipStream_t stream) {
    const float* x  = (const float*)d_in[0];
    const int*   ei = (const int*)d_in[1];
    const float* ea = (const float*)d_in[2];
    const float* W1 = (const float*)d_in[3];
    const float* b1 = (const float*)d_in[4];
    const float* W2 = (const float*)d_in[5];
    const float* b2 = (const float*)d_in[6];
    float* out = (float*)d_out;

    char* wsb = (char*)d_ws;
    unsigned int*   hsum   = (unsigned int*)  (wsb + OFF_HSUM);
    _Float16*       z      = (_Float16*)      (wsb + OFF_Z);
    float4*         crec   = (float4*)        (wsb + OFF_CREC);
    float*          cnt    = (float*)         (wsb + OFF_CNT);
    unsigned char*  ntype  = (unsigned char*) (wsb + OFF_NTYPE);
    unsigned*       cursor = (unsigned*)      (wsb + OFF_CURSOR);

    // zero hsum/cnt/cursor
    gnn_prep0<<<(825001 + 255) / 256, 256, 0, stream>>>(
        (uint4*)hsum, (float4*)cnt, cursor);

    // node-level W1 pre-GEMM (reads x f32 directly) + ntype side effect
    gnn_zgemm<<<(N_NODES + 127) / 128, 256, 0, stream>>>(x, W1, z, ntype);

    // masked-edge compaction (wave-ballot, unordered) + cnt
    gnn_compact<<<N_EDGES / 256, 256, 0, stream>>>(ei, ea, ntype, cursor, crec, cnt);

    // edge phase: batched quad-per-edge gather + coalesced packed-f16 atomics
    gnn_edge_quad2<<<2048, 256, 0, stream>>>(crec, cursor, z, W1, b1, hsum);

    // node-level layer 2 + relu via MFMA
    gnn_node_out<<<(N_NODES + 127) / 128, 256, 0, stream>>>(
        (const _Float16*)hsum, cnt, W2, b2, out);
}

// Round 11
// 391.849 us; speedup vs baseline: 1.5016x; 1.5016x over previous
//
#include <hip/hip_runtime.h>

#define N_NODES 100000
#define N_EDGES 1600000
#define IN_CH   64
#define HID_CH  64
#define OUT_CH  128
#define NSEG    64
#define SEG_CAP 16000            // mean fill 15015, sigma~77 -> 12.7 sigma margin

typedef __attribute__((ext_vector_type(8))) __bf16    bf16x8;
typedef __attribute__((ext_vector_type(4))) float     f32x4;
typedef __attribute__((ext_vector_type(2))) _Float16  f16x2;
typedef __attribute__((ext_vector_type(8))) _Float16  f16x8;

// ---- workspace byte offsets (total ~55.3 MB) ----
#define OFF_HSUM   0            // 100000*64*2  = 12,800,000 (f16 pairs, natural order)
#define OFF_Z      12800000     // 100000*128*2 = 25,600,000 (f16: [0:64]=dst-half, [64:128]=src-half)
#define OFF_CREC   38400000     // 64*16000*16  = 16,384,000 (segmented compacted records)
#define OFF_CNT    54784000     // 100000*4
#define OFF_NTYPE  55184000     // 100000*1
#define OFF_CURS   55284000     // 64*4 (16B-aligned)

__device__ __forceinline__ unsigned short f2bf(float f) {
    union { float f; unsigned int i; } c;
    c.f = f;
    unsigned int u = c.i;
    unsigned int r = (u + 0x7FFFu + ((u >> 16) & 1u)) >> 16;   // RNE
    return (unsigned short)r;
}

// packed fp16 atomic add (global_atomic_pk_add_f16, gfx90a+)
__device__ __forceinline__ void atomic_pk_add_f16(unsigned int* addr, f16x2 val) {
    typedef __attribute__((address_space(1))) f16x2 gf16x2;
    __builtin_amdgcn_global_atomic_fadd_v2f16((gf16x2*)(void*)addr, val);
}

// prep0: zero hsum + cnt + segment cursors (pure memset).
__global__ void gnn_prep0(uint4* __restrict__ hz,      // hsum as uint4 (800k)
                          float4* __restrict__ cz,     // cnt as float4 (25k)
                          unsigned* __restrict__ curs) {
    int i = blockIdx.x * blockDim.x + threadIdx.x;
    if (i < 800000) {
        hz[i] = (uint4){0u, 0u, 0u, 0u};
    } else if (i < 825000) {
        cz[i - 800000] = (float4){0.f, 0.f, 0.f, 0.f};
    } else if (i < 825000 + NSEG) {
        curs[i - 825000] = 0u;
    }
}

// zgemm: z[n][j] = sum_k x[n][k]*Bc[k][j]; Bc[k][j<64]=W1[k][j] (dst half),
// Bc[k][j>=64]=W1[64+k][j-64] (src half). Reads x f32 directly; writes ntype
// byte table as a side effect (q==0 lanes hold x[node][0]).
__global__ __launch_bounds__(256, 4) void gnn_zgemm(
    const float* __restrict__ x,     // [N_NODES][64] f32
    const float* __restrict__ W1,    // [131][64]
    _Float16*    __restrict__ z,     // [N_NODES][128]
    unsigned char* __restrict__ ntype)
{
    __shared__ __align__(16) unsigned short BT[128][72];  // BT[j][k]=Bc[k][j]

    const int tid  = threadIdx.x;
    const int wave = tid >> 6;
    const int lane = tid & 63;
    const int q    = lane >> 4;
    const int m16  = lane & 15;

    for (int idx = tid; idx < 64 * 128; idx += 256) {
        int k = idx >> 7, j = idx & 127;
        BT[j][k] = f2bf(W1[(k + ((j >= 64) ? 64 : 0)) * 64 + (j & 63)]);
    }
    __syncthreads();

    const int nodeBase = (blockIdx.x * 4 + wave) * 32;
    if (nodeBase >= N_NODES) return;

    f32x4 acc[2][8];
#pragma unroll
    for (int mt = 0; mt < 2; ++mt)
#pragma unroll
        for (int nt = 0; nt < 8; ++nt)
            acc[mt][nt] = (f32x4){0.0f, 0.0f, 0.0f, 0.0f};

#pragma unroll
    for (int kc = 0; kc < 2; ++kc) {
        bf16x8 af[2];
#pragma unroll
        for (int mt = 0; mt < 2; ++mt) {
            int node = nodeBase + mt * 16 + m16;
            if (node >= N_NODES) node = N_NODES - 1;   // clamp; rows unused
            const float4* xr = reinterpret_cast<const float4*>(
                x + (size_t)node * 64 + kc * 32 + q * 8);
            float4 xa = xr[0], xb = xr[1];
            union { bf16x8 v; unsigned short u[8]; } rr;
            rr.u[0] = f2bf(xa.x); rr.u[1] = f2bf(xa.y);
            rr.u[2] = f2bf(xa.z); rr.u[3] = f2bf(xa.w);
            rr.u[4] = f2bf(xb.x); rr.u[5] = f2bf(xb.y);
            rr.u[6] = f2bf(xb.z); rr.u[7] = f2bf(xb.w);
            af[mt] = rr.v;
            if (kc == 0 && q == 0)   // xa.x = x[node][0] = node type
                ntype[node] = (xa.x == 0.0f) ? 0 : ((xa.x == 1.0f) ? 1 : 2);
        }
#pragma unroll
        for (int nt = 0; nt < 8; ++nt) {
            bf16x8 bfr = *reinterpret_cast<const bf16x8*>(
                &BT[nt * 16 + m16][kc * 32 + q * 8]);
            acc[0][nt] = __builtin_amdgcn_mfma_f32_16x16x32_bf16(af[0], bfr, acc[0][nt], 0, 0, 0);
            acc[1][nt] = __builtin_amdgcn_mfma_f32_16x16x32_bf16(af[1], bfr, acc[1][nt], 0, 0, 0);
        }
    }

    // C-layout: row = q*4+r, col = nt*16+m16
#pragma unroll
    for (int mt = 0; mt < 2; ++mt) {
#pragma unroll
        for (int nt = 0; nt < 8; ++nt) {
            int col = nt * 16 + m16;
#pragma unroll
            for (int r = 0; r < 4; ++r) {
                int n = nodeBase + mt * 16 + q * 4 + r;
                if (n < N_NODES)
                    z[(size_t)n * 128 + col] = (_Float16)acc[mt][nt][r];
            }
        }
    }
}

// compact: masked-in edges -> 64 SEGMENTED record arrays via wave-ballot +
// one leader atomic per wave to cursor[wid & 63]. Round-10's single global
// cursor serialized 25000 same-address RMWs (14ns each = 356us!); 64-way
// sharding cuts per-address contention to ~390 — overlapped across addresses.
// Record = {s, d, a0, a1|a2 f16}. Also bumps cnt[d] (distributed atomics).
__global__ void gnn_compact(const int* __restrict__ eidx,
                            const float* __restrict__ ea,
                            const unsigned char* __restrict__ ntype,
                            unsigned* __restrict__ curs,   // [NSEG]
                            float4* __restrict__ crec,     // [NSEG][SEG_CAP]
                            float* __restrict__ cnt) {
    int e = blockIdx.x * 256 + threadIdx.x;   // N_EDGES % 256 == 0
    int lane = threadIdx.x & 63;
    int wid  = (blockIdx.x * 256 + threadIdx.x) >> 6;
    int seg  = wid & (NSEG - 1);

    int s = eidx[e];
    float a0 = ea[e * 3];
    int ntc = ntype[s];
    bool mk = (ntc == 0) ? (a0 < 0.5f) : ((ntc == 1) ? (a0 < 0.3f) : true);

    unsigned long long bal = __ballot(mk);
    int nact = __popcll(bal);
    if (nact == 0) return;                     // wave-uniform
    int prefix = __popcll(bal & ((1ULL << lane) - 1ULL));
    int leader = __ffsll((long long)bal) - 1;
    unsigned base = 0;
    if (lane == leader) base = atomicAdd(curs + seg, (unsigned)nact);
    base = __shfl(base, leader);

    if (mk) {
        unsigned pos = base + (unsigned)prefix;
        if (pos < SEG_CAP) {                   // 12.7-sigma margin; never in practice
            int d = eidx[N_EDGES + e];
            union { f16x2 v; float f; } pk;
            pk.v = (f16x2){(_Float16)ea[e * 3 + 1], (_Float16)ea[e * 3 + 2]};
            float4 rec;
            rec.x = __int_as_float(s);
            rec.y = __int_as_float(d);
            rec.z = a0;
            rec.w = pk.f;
            crec[(size_t)seg * SEG_CAP + pos] = rec;
            unsafeAtomicAdd(&cnt[d], 1.0f);
        }
    }
}

// edge_quad2: quad-per-edge (coalesced 64B atomic/gather geometry), batched x4,
// segmented input. 2048 blocks * 16 quads = 32768 quads = 64 segs * 512 quads:
// quad gq works segment gq>>9, grid-striding within it — all quads active.
// Phases per iteration: 4 record loads -> 16 z-gathers -> compute -> 8 atomics.
__global__ __launch_bounds__(256, 4) void gnn_edge_quad2(
    const float4*   __restrict__ crec,   // [NSEG][SEG_CAP]
    const unsigned* __restrict__ curs,   // [NSEG] record counts
    const _Float16* __restrict__ z,      // [N_NODES][128]
    const float*    __restrict__ W1,     // [131][64]
    const float*    __restrict__ b1,     // [64]
    unsigned int*   __restrict__ hsum)   // [N_NODES][32] f16 pairs (natural)
{
    const int tid = threadIdx.x;
    const int m16 = tid & 15;
    const int c0  = 2 * m16;

    // per-lane weight tail in registers: channels c0, c0+1, c0+32, c0+33
    const float wx0 = W1[128 * 64 + c0],      wx1 = W1[128 * 64 + c0 + 1];
    const float wx2 = W1[128 * 64 + c0 + 32], wx3 = W1[128 * 64 + c0 + 33];
    const float wy0 = W1[129 * 64 + c0],      wy1 = W1[129 * 64 + c0 + 1];
    const float wy2 = W1[129 * 64 + c0 + 32], wy3 = W1[129 * 64 + c0 + 33];
    const float wz0 = W1[130 * 64 + c0],      wz1 = W1[130 * 64 + c0 + 1];
    const float wz2 = W1[130 * 64 + c0 + 32], wz3 = W1[130 * 64 + c0 + 33];
    const float bb0 = b1[c0],                 bb1 = b1[c0 + 1];
    const float bb2 = b1[c0 + 32],            bb3 = b1[c0 + 33];

    const int gq     = (blockIdx.x * 256 + tid) >> 4;   // global quad id 0..32767
    const int seg    = gq >> 9;                         // 512 quads per segment
    const int qInSeg = gq & 511;
    if (seg >= NSEG) return;

    int nseg = (int)curs[seg];
    if (nseg > SEG_CAP) nseg = SEG_CAP;
    const float4* sbase = crec + (size_t)seg * SEG_CAP;

    for (int i0 = qInSeg * 4; i0 < nseg; i0 += 512 * 4) {
        // ---- phase 1: up to 4 record loads (quad-uniform addresses) ----
        float4 rec[4];
        bool   v[4];
        int    s[4], d[4];
#pragma unroll
        for (int k = 0; k < 4; ++k) {
            int i = i0 + k;
            v[k] = (i < nseg);
            rec[k] = v[k] ? sbase[i] : (float4){0.f, 0.f, 0.f, 0.f};
            s[k] = __float_as_int(rec[k].x);   // 0 when invalid -> safe gather
            d[k] = __float_as_int(rec[k].y);
        }

        // ---- phase 2: 16 independent z-gathers (64B-contiguous per quad) ----
        f16x2 zd01[4], zd23[4], zs01[4], zs23[4];
#pragma unroll
        for (int k = 0; k < 4; ++k) {
            const _Float16* zd = z + (size_t)d[k] * 128;        // dst half
            const _Float16* zs = z + (size_t)s[k] * 128 + 64;   // src half
            zd01[k] = *reinterpret_cast<const f16x2*>(zd + c0);
            zd23[k] = *reinterpret_cast<const f16x2*>(zd + c0 + 32);
            zs01[k] = *reinterpret_cast<const f16x2*>(zs + c0);
            zs23[k] = *reinterpret_cast<const f16x2*>(zs + c0 + 32);
        }

        // ---- phase 3+4: compute + coalesced packed-f16 atomics ----
#pragma unroll
        for (int k = 0; k < 4; ++k) {
            if (!v[k]) continue;               // tail only
            float a0 = rec[k].z;
            union { float f; f16x2 v2; } pk; pk.f = rec[k].w;
            float a1 = (float)pk.v2[0];
            float a2 = (float)pk.v2[1];

            float h0 = (float)zd01[k][0] + (float)zs01[k][0] + bb0 + a0 * wx0 + a1 * wy0 + a2 * wz0;
            float h1 = (float)zd01[k][1] + (float)zs01[k][1] + bb1 + a0 * wx1 + a1 * wy1 + a2 * wz1;
            float h2 = (float)zd23[k][0] + (float)zs23[k][0] + bb2 + a0 * wx2 + a1 * wy2 + a2 * wz2;
            float h3 = (float)zd23[k][1] + (float)zs23[k][1] + bb3 + a0 * wx3 + a1 * wy3 + a2 * wz3;
            h0 = h0 > 0.f ? h0 : 0.f;
            h1 = h1 > 0.f ? h1 : 0.f;
            h2 = h2 > 0.f ? h2 : 0.f;
            h3 = h3 > 0.f ? h3 : 0.f;

            unsigned int* hb = hsum + (size_t)d[k] * 32;
            if (h0 + h1 > 0.f) {               // quad covers dwords 0..15
                f16x2 p = {(_Float16)h0, (_Float16)h1};
                atomic_pk_add_f16(hb + m16, p);
            }
            if (h2 + h3 > 0.f) {               // quad covers dwords 16..31
                f16x2 p = {(_Float16)h2, (_Float16)h3};
                atomic_pk_add_f16(hb + 16 + m16, p);
            }
        }
    }
}

// Node kernel (MFMA): out[n] = relu(hsum[n] @ W2 + cnt[n]*b2). (r9-verified)
__global__ __launch_bounds__(256, 4) void gnn_node_out(
    const _Float16* __restrict__ hsum,  // [N_NODES][64] f16, natural order
    const float*    __restrict__ cnt,   // [N_NODES]
    const float*    __restrict__ W2,    // [64][128]
    const float*    __restrict__ b2,    // [128]
    float*          __restrict__ out)   // [N_NODES][128]
{
    __shared__ __align__(16) unsigned short W2T[128][72];  // W2T[n][k]=W2[k][n]
    __shared__ float b2s[128];

    const int tid  = threadIdx.x;
    const int wave = tid >> 6;
    const int lane = tid & 63;
    const int q    = lane >> 4;
    const int m16  = lane & 15;

    const int nodeBase = (blockIdx.x * 4 + wave) * 32;

    // prefetch this wave's hsum rows + cnt before LDS staging (hide HBM latency)
    f16x8 hpre[2][2];
    float cc[2][4];
#pragma unroll
    for (int kc = 0; kc < 2; ++kc)
#pragma unroll
        for (int mt = 0; mt < 2; ++mt) {
            int node = nodeBase + mt * 16 + m16;
            if (node >= N_NODES) node = N_NODES - 1;
            hpre[kc][mt] = *reinterpret_cast<const f16x8*>(
                hsum + (size_t)node * HID_CH + kc * 32 + q * 8);
        }
#pragma unroll
    for (int mt = 0; mt < 2; ++mt)
#pragma unroll
        for (int r = 0; r < 4; ++r) {
            int n = nodeBase + mt * 16 + q * 4 + r;
            cc[mt][r] = (n < N_NODES) ? cnt[n] : 0.0f;
        }

    for (int idx = tid; idx < 64 * 128; idx += 256) {
        int k = idx >> 7, n = idx & 127;
        W2T[n][k] = f2bf(W2[k * 128 + n]);
    }
    if (tid < 128) b2s[tid] = b2[tid];
    __syncthreads();

    if (nodeBase >= N_NODES) return;

    f32x4 acc[2][8];
#pragma unroll
    for (int mt = 0; mt < 2; ++mt)
#pragma unroll
        for (int nt = 0; nt < 8; ++nt)
            acc[mt][nt] = (f32x4){0.0f, 0.0f, 0.0f, 0.0f};

#pragma unroll
    for (int kc = 0; kc < 2; ++kc) {
        bf16x8 af[2];
#pragma unroll
        for (int mt = 0; mt < 2; ++mt) {
            union { bf16x8 v; unsigned short u[8]; } rr;
#pragma unroll
            for (int j = 0; j < 8; ++j) rr.u[j] = f2bf((float)hpre[kc][mt][j]);
            af[mt] = rr.v;
        }
#pragma unroll
        for (int nt = 0; nt < 8; ++nt) {
            bf16x8 bfr = *reinterpret_cast<const bf16x8*>(
                &W2T[nt * 16 + m16][kc * 32 + q * 8]);
            acc[0][nt] = __builtin_amdgcn_mfma_f32_16x16x32_bf16(af[0], bfr, acc[0][nt], 0, 0, 0);
            acc[1][nt] = __builtin_amdgcn_mfma_f32_16x16x32_bf16(af[1], bfr, acc[1][nt], 0, 0, 0);
        }
    }

#pragma unroll
    for (int mt = 0; mt < 2; ++mt) {
        int nn[4];
#pragma unroll
        for (int r = 0; r < 4; ++r)
            nn[r] = nodeBase + mt * 16 + q * 4 + r;
#pragma unroll
        for (int nt = 0; nt < 8; ++nt) {
            int col = nt * 16 + m16;
            float bb = b2s[col];
#pragma unroll
            for (int r = 0; r < 4; ++r) {
                if (nn[r] < N_NODES) {
                    float v = acc[mt][nt][r] + cc[mt][r] * bb;
                    out[(size_t)nn[r] * OUT_CH + col] = v > 0.0f ? v : 0.0f;
                }
            }
        }
    }
}

extern "C" void kernel_launch(void* const* d_in, const int* in_sizes, int n_in,
                              void* d_out, int out_size, void* d_ws, size_t ws_size,
                              hipStream_t stream) {
    const float* x  = (const float*)d_in[0];
    const int*   ei = (const int*)d_in[1];
    const float* ea = (const float*)d_in[2];
    const float* W1 = (const float*)d_in[3];
    const float* b1 = (const float*)d_in[4];
    const float* W2 = (const float*)d_in[5];
    const float* b2 = (const float*)d_in[6];
    float* out = (float*)d_out;

    char* wsb = (char*)d_ws;
    unsigned int*   hsum   = (unsigned int*)  (wsb + OFF_HSUM);
    _Float16*       z      = (_Float16*)      (wsb + OFF_Z);
    float4*         crec   = (float4*)        (wsb + OFF_CREC);
    float*          cnt    = (float*)         (wsb + OFF_CNT);
    unsigned char*  ntype  = (unsigned char*) (wsb + OFF_NTYPE);
    unsigned*       curs   = (unsigned*)      (wsb + OFF_CURS);

    // zero hsum/cnt/cursors
    gnn_prep0<<<(825000 + NSEG + 255) / 256, 256, 0, stream>>>(
        (uint4*)hsum, (float4*)cnt, curs);

    // node-level W1 pre-GEMM (reads x f32 directly) + ntype side effect
    gnn_zgemm<<<(N_NODES + 127) / 128, 256, 0, stream>>>(x, W1, z, ntype);

    // masked-edge compaction: 64-way sharded cursors (r10: 1 cursor = 356us)
    gnn_compact<<<N_EDGES / 256, 256, 0, stream>>>(ei, ea, ntype, curs, crec, cnt);

    // edge phase: batched quad-per-edge gather + coalesced packed-f16 atomics
    gnn_edge_quad2<<<2048, 256, 0, stream>>>(crec, curs, z, W1, b1, hsum);

    // node-level layer 2 + relu via MFMA
    gnn_node_out<<<(N_NODES + 127) / 128, 256, 0, stream>>>(
        (const _Float16*)hsum, cnt, W2, b2, out);
}

// Round 12
// 292.858 us; speedup vs baseline: 2.0092x; 1.3380x over previous
//
#include <hip/hip_runtime.h>

#define N_NODES 100000
#define N_EDGES 1600000
#define IN_CH   64
#define HID_CH  64
#define OUT_CH  128
#define NSEG    64
#define SEG_CAP 16000            // mean fill 15015, sigma~77 -> 12.7 sigma margin
#define CUR_STRIDE 256           // dwords: 1KB per cursor -> no line/bank sharing

typedef __attribute__((ext_vector_type(8))) __bf16    bf16x8;
typedef __attribute__((ext_vector_type(4))) float     f32x4;
typedef __attribute__((ext_vector_type(2))) _Float16  f16x2;
typedef __attribute__((ext_vector_type(8))) _Float16  f16x8;

// ---- workspace byte offsets (total ~55.4 MB) ----
#define OFF_HSUM   0            // 100000*64*2  = 12,800,000 (f16 pairs, natural order)
#define OFF_Z      12800000     // 100000*128*2 = 25,600,000 (f16: [0:64]=dst-half, [64:128]=src-half)
#define OFF_CREC   38400000     // 64*16000*16  = 16,384,000 (segmented compacted records)
#define OFF_CNT    54784000     // 100000*4
#define OFF_NTYPE  55184000     // 100000*1
#define OFF_CURS   55284000     // 64*1024B = 65,536 (padded cursors; 16B-aligned)

__device__ __forceinline__ unsigned short f2bf(float f) {
    union { float f; unsigned int i; } c;
    c.f = f;
    unsigned int u = c.i;
    unsigned int r = (u + 0x7FFFu + ((u >> 16) & 1u)) >> 16;   // RNE
    return (unsigned short)r;
}

// packed fp16 atomic add (global_atomic_pk_add_f16, gfx90a+)
__device__ __forceinline__ void atomic_pk_add_f16(unsigned int* addr, f16x2 val) {
    typedef __attribute__((address_space(1))) f16x2 gf16x2;
    __builtin_amdgcn_global_atomic_fadd_v2f16((gf16x2*)(void*)addr, val);
}

// prep0: zero hsum + cnt + padded cursor area (pure memset).
__global__ void gnn_prep0(uint4* __restrict__ hz,      // hsum as uint4 (800k)
                          float4* __restrict__ cz,     // cnt as float4 (25k)
                          uint4* __restrict__ cursv) { // cursor area as uint4 (4096)
    int i = blockIdx.x * blockDim.x + threadIdx.x;
    if (i < 800000) {
        hz[i] = (uint4){0u, 0u, 0u, 0u};
    } else if (i < 825000) {
        cz[i - 800000] = (float4){0.f, 0.f, 0.f, 0.f};
    } else if (i < 825000 + 4096) {
        cursv[i - 825000] = (uint4){0u, 0u, 0u, 0u};
    }
}

// zgemm: z[n][j] = sum_k x[n][k]*Bc[k][j]; Bc[k][j<64]=W1[k][j] (dst half),
// Bc[k][j>=64]=W1[64+k][j-64] (src half). Reads x f32 directly; writes ntype
// byte table as a side effect (q==0 lanes hold x[node][0]).
__global__ __launch_bounds__(256, 4) void gnn_zgemm(
    const float* __restrict__ x,     // [N_NODES][64] f32
    const float* __restrict__ W1,    // [131][64]
    _Float16*    __restrict__ z,     // [N_NODES][128]
    unsigned char* __restrict__ ntype)
{
    __shared__ __align__(16) unsigned short BT[128][72];  // BT[j][k]=Bc[k][j]

    const int tid  = threadIdx.x;
    const int wave = tid >> 6;
    const int lane = tid & 63;
    const int q    = lane >> 4;
    const int m16  = lane & 15;

    for (int idx = tid; idx < 64 * 128; idx += 256) {
        int k = idx >> 7, j = idx & 127;
        BT[j][k] = f2bf(W1[(k + ((j >= 64) ? 64 : 0)) * 64 + (j & 63)]);
    }
    __syncthreads();

    const int nodeBase = (blockIdx.x * 4 + wave) * 32;
    if (nodeBase >= N_NODES) return;

    f32x4 acc[2][8];
#pragma unroll
    for (int mt = 0; mt < 2; ++mt)
#pragma unroll
        for (int nt = 0; nt < 8; ++nt)
            acc[mt][nt] = (f32x4){0.0f, 0.0f, 0.0f, 0.0f};

#pragma unroll
    for (int kc = 0; kc < 2; ++kc) {
        bf16x8 af[2];
#pragma unroll
        for (int mt = 0; mt < 2; ++mt) {
            int node = nodeBase + mt * 16 + m16;
            if (node >= N_NODES) node = N_NODES - 1;   // clamp; rows unused
            const float4* xr = reinterpret_cast<const float4*>(
                x + (size_t)node * 64 + kc * 32 + q * 8);
            float4 xa = xr[0], xb = xr[1];
            union { bf16x8 v; unsigned short u[8]; } rr;
            rr.u[0] = f2bf(xa.x); rr.u[1] = f2bf(xa.y);
            rr.u[2] = f2bf(xa.z); rr.u[3] = f2bf(xa.w);
            rr.u[4] = f2bf(xb.x); rr.u[5] = f2bf(xb.y);
            rr.u[6] = f2bf(xb.z); rr.u[7] = f2bf(xb.w);
            af[mt] = rr.v;
            if (kc == 0 && q == 0)   // xa.x = x[node][0] = node type
                ntype[node] = (xa.x == 0.0f) ? 0 : ((xa.x == 1.0f) ? 1 : 2);
        }
#pragma unroll
        for (int nt = 0; nt < 8; ++nt) {
            bf16x8 bfr = *reinterpret_cast<const bf16x8*>(
                &BT[nt * 16 + m16][kc * 32 + q * 8]);
            acc[0][nt] = __builtin_amdgcn_mfma_f32_16x16x32_bf16(af[0], bfr, acc[0][nt], 0, 0, 0);
            acc[1][nt] = __builtin_amdgcn_mfma_f32_16x16x32_bf16(af[1], bfr, acc[1][nt], 0, 0, 0);
        }
    }

    // C-layout: row = q*4+r, col = nt*16+m16
#pragma unroll
    for (int mt = 0; mt < 2; ++mt) {
#pragma unroll
        for (int nt = 0; nt < 8; ++nt) {
            int col = nt * 16 + m16;
#pragma unroll
            for (int r = 0; r < 4; ++r) {
                int n = nodeBase + mt * 16 + q * 4 + r;
                if (n < N_NODES)
                    z[(size_t)n * 128 + col] = (_Float16)acc[mt][nt][r];
            }
        }
    }
}

// compact: masked-in edges -> 64 SEGMENTED record arrays via wave-ballot +
// one leader atomic per wave to its segment's cursor. FALSE-SHARING FIX:
// r11 packed 64 cursors into 256B (2-4 cache lines) — atomic RMW serializes
// per LINE at the coherence point, so 64 "shards" gave only ~4-way overlap
// (162us). Cursors now live 1KB apart: 64 independent lines -> ~390 atomics
// per line, overlapped -> ~5us.
__global__ void gnn_compact(const int* __restrict__ eidx,
                            const float* __restrict__ ea,
                            const unsigned char* __restrict__ ntype,
                            unsigned* __restrict__ curs,   // [NSEG*CUR_STRIDE]
                            float4* __restrict__ crec,     // [NSEG][SEG_CAP]
                            float* __restrict__ cnt) {
    int e = blockIdx.x * 256 + threadIdx.x;   // N_EDGES % 256 == 0
    int lane = threadIdx.x & 63;
    int wid  = (blockIdx.x * 256 + threadIdx.x) >> 6;
    int seg  = wid & (NSEG - 1);

    int s = eidx[e];
    float a0 = ea[e * 3];
    int ntc = ntype[s];
    bool mk = (ntc == 0) ? (a0 < 0.5f) : ((ntc == 1) ? (a0 < 0.3f) : true);

    unsigned long long bal = __ballot(mk);
    int nact = __popcll(bal);
    if (nact == 0) return;                     // wave-uniform
    int prefix = __popcll(bal & ((1ULL << lane) - 1ULL));
    int leader = __ffsll((long long)bal) - 1;
    unsigned base = 0;
    if (lane == leader) base = atomicAdd(curs + seg * CUR_STRIDE, (unsigned)nact);
    base = __shfl(base, leader);

    if (mk) {
        unsigned pos = base + (unsigned)prefix;
        if (pos < SEG_CAP) {                   // 12.7-sigma margin; never in practice
            int d = eidx[N_EDGES + e];
            union { f16x2 v; float f; } pk;
            pk.v = (f16x2){(_Float16)ea[e * 3 + 1], (_Float16)ea[e * 3 + 2]};
            float4 rec;
            rec.x = __int_as_float(s);
            rec.y = __int_as_float(d);
            rec.z = a0;
            rec.w = pk.f;
            crec[(size_t)seg * SEG_CAP + pos] = rec;
            unsafeAtomicAdd(&cnt[d], 1.0f);
        }
    }
}

// edge_quad2: quad-per-edge (coalesced 64B atomic/gather geometry), batched x4,
// segmented input. 2048 blocks * 16 quads = 32768 quads = 64 segs * 512 quads:
// quad gq works segment gq>>9, grid-striding within it — all quads active.
// Phases per iteration: 4 record loads -> 16 z-gathers -> compute -> 8 atomics.
__global__ __launch_bounds__(256, 4) void gnn_edge_quad2(
    const float4*   __restrict__ crec,   // [NSEG][SEG_CAP]
    const unsigned* __restrict__ curs,   // [NSEG*CUR_STRIDE] record counts
    const _Float16* __restrict__ z,      // [N_NODES][128]
    const float*    __restrict__ W1,     // [131][64]
    const float*    __restrict__ b1,     // [64]
    unsigned int*   __restrict__ hsum)   // [N_NODES][32] f16 pairs (natural)
{
    const int tid = threadIdx.x;
    const int m16 = tid & 15;
    const int c0  = 2 * m16;

    // per-lane weight tail in registers: channels c0, c0+1, c0+32, c0+33
    const float wx0 = W1[128 * 64 + c0],      wx1 = W1[128 * 64 + c0 + 1];
    const float wx2 = W1[128 * 64 + c0 + 32], wx3 = W1[128 * 64 + c0 + 33];
    const float wy0 = W1[129 * 64 + c0],      wy1 = W1[129 * 64 + c0 + 1];
    const float wy2 = W1[129 * 64 + c0 + 32], wy3 = W1[129 * 64 + c0 + 33];
    const float wz0 = W1[130 * 64 + c0],      wz1 = W1[130 * 64 + c0 + 1];
    const float wz2 = W1[130 * 64 + c0 + 32], wz3 = W1[130 * 64 + c0 + 33];
    const float bb0 = b1[c0],                 bb1 = b1[c0 + 1];
    const float bb2 = b1[c0 + 32],            bb3 = b1[c0 + 33];

    const int gq     = (blockIdx.x * 256 + tid) >> 4;   // global quad id 0..32767
    const int seg    = gq >> 9;                         // 512 quads per segment
    const int qInSeg = gq & 511;
    if (seg >= NSEG) return;

    int nseg = (int)curs[seg * CUR_STRIDE];
    if (nseg > SEG_CAP) nseg = SEG_CAP;
    const float4* sbase = crec + (size_t)seg * SEG_CAP;

    for (int i0 = qInSeg * 4; i0 < nseg; i0 += 512 * 4) {
        // ---- phase 1: up to 4 record loads (quad-uniform addresses) ----
        float4 rec[4];
        bool   v[4];
        int    s[4], d[4];
#pragma unroll
        for (int k = 0; k < 4; ++k) {
            int i = i0 + k;
            v[k] = (i < nseg);
            rec[k] = v[k] ? sbase[i] : (float4){0.f, 0.f, 0.f, 0.f};
            s[k] = __float_as_int(rec[k].x);   // 0 when invalid -> safe gather
            d[k] = __float_as_int(rec[k].y);
        }

        // ---- phase 2: 16 independent z-gathers (64B-contiguous per quad) ----
        f16x2 zd01[4], zd23[4], zs01[4], zs23[4];
#pragma unroll
        for (int k = 0; k < 4; ++k) {
            const _Float16* zd = z + (size_t)d[k] * 128;        // dst half
            const _Float16* zs = z + (size_t)s[k] * 128 + 64;   // src half
            zd01[k] = *reinterpret_cast<const f16x2*>(zd + c0);
            zd23[k] = *reinterpret_cast<const f16x2*>(zd + c0 + 32);
            zs01[k] = *reinterpret_cast<const f16x2*>(zs + c0);
            zs23[k] = *reinterpret_cast<const f16x2*>(zs + c0 + 32);
        }

        // ---- phase 3+4: compute + coalesced packed-f16 atomics ----
#pragma unroll
        for (int k = 0; k < 4; ++k) {
            if (!v[k]) continue;               // tail only
            float a0 = rec[k].z;
            union { float f; f16x2 v2; } pk; pk.f = rec[k].w;
            float a1 = (float)pk.v2[0];
            float a2 = (float)pk.v2[1];

            float h0 = (float)zd01[k][0] + (float)zs01[k][0] + bb0 + a0 * wx0 + a1 * wy0 + a2 * wz0;
            float h1 = (float)zd01[k][1] + (float)zs01[k][1] + bb1 + a0 * wx1 + a1 * wy1 + a2 * wz1;
            float h2 = (float)zd23[k][0] + (float)zs23[k][0] + bb2 + a0 * wx2 + a1 * wy2 + a2 * wz2;
            float h3 = (float)zd23[k][1] + (float)zs23[k][1] + bb3 + a0 * wx3 + a1 * wy3 + a2 * wz3;
            h0 = h0 > 0.f ? h0 : 0.f;
            h1 = h1 > 0.f ? h1 : 0.f;
            h2 = h2 > 0.f ? h2 : 0.f;
            h3 = h3 > 0.f ? h3 : 0.f;

            unsigned int* hb = hsum + (size_t)d[k] * 32;
            if (h0 + h1 > 0.f) {               // quad covers dwords 0..15
                f16x2 p = {(_Float16)h0, (_Float16)h1};
                atomic_pk_add_f16(hb + m16, p);
            }
            if (h2 + h3 > 0.f) {               // quad covers dwords 16..31
                f16x2 p = {(_Float16)h2, (_Float16)h3};
                atomic_pk_add_f16(hb + 16 + m16, p);
            }
        }
    }
}

// Node kernel (MFMA): out[n] = relu(hsum[n] @ W2 + cnt[n]*b2). (r9-verified)
__global__ __launch_bounds__(256, 4) void gnn_node_out(
    const _Float16* __restrict__ hsum,  // [N_NODES][64] f16, natural order
    const float*    __restrict__ cnt,   // [N_NODES]
    const float*    __restrict__ W2,    // [64][128]
    const float*    __restrict__ b2,    // [128]
    float*          __restrict__ out)   // [N_NODES][128]
{
    __shared__ __align__(16) unsigned short W2T[128][72];  // W2T[n][k]=W2[k][n]
    __shared__ float b2s[128];

    const int tid  = threadIdx.x;
    const int wave = tid >> 6;
    const int lane = tid & 63;
    const int q    = lane >> 4;
    const int m16  = lane & 15;

    const int nodeBase = (blockIdx.x * 4 + wave) * 32;

    // prefetch this wave's hsum rows + cnt before LDS staging (hide HBM latency)
    f16x8 hpre[2][2];
    float cc[2][4];
#pragma unroll
    for (int kc = 0; kc < 2; ++kc)
#pragma unroll
        for (int mt = 0; mt < 2; ++mt) {
            int node = nodeBase + mt * 16 + m16;
            if (node >= N_NODES) node = N_NODES - 1;
            hpre[kc][mt] = *reinterpret_cast<const f16x8*>(
                hsum + (size_t)node * HID_CH + kc * 32 + q * 8);
        }
#pragma unroll
    for (int mt = 0; mt < 2; ++mt)
#pragma unroll
        for (int r = 0; r < 4; ++r) {
            int n = nodeBase + mt * 16 + q * 4 + r;
            cc[mt][r] = (n < N_NODES) ? cnt[n] : 0.0f;
        }

    for (int idx = tid; idx < 64 * 128; idx += 256) {
        int k = idx >> 7, n = idx & 127;
        W2T[n][k] = f2bf(W2[k * 128 + n]);
    }
    if (tid < 128) b2s[tid] = b2[tid];
    __syncthreads();

    if (nodeBase >= N_NODES) return;

    f32x4 acc[2][8];
#pragma unroll
    for (int mt = 0; mt < 2; ++mt)
#pragma unroll
        for (int nt = 0; nt < 8; ++nt)
            acc[mt][nt] = (f32x4){0.0f, 0.0f, 0.0f, 0.0f};

#pragma unroll
    for (int kc = 0; kc < 2; ++kc) {
        bf16x8 af[2];
#pragma unroll
        for (int mt = 0; mt < 2; ++mt) {
            union { bf16x8 v; unsigned short u[8]; } rr;
#pragma unroll
            for (int j = 0; j < 8; ++j) rr.u[j] = f2bf((float)hpre[kc][mt][j]);
            af[mt] = rr.v;
        }
#pragma unroll
        for (int nt = 0; nt < 8; ++nt) {
            bf16x8 bfr = *reinterpret_cast<const bf16x8*>(
                &W2T[nt * 16 + m16][kc * 32 + q * 8]);
            acc[0][nt] = __builtin_amdgcn_mfma_f32_16x16x32_bf16(af[0], bfr, acc[0][nt], 0, 0, 0);
            acc[1][nt] = __builtin_amdgcn_mfma_f32_16x16x32_bf16(af[1], bfr, acc[1][nt], 0, 0, 0);
        }
    }

#pragma unroll
    for (int mt = 0; mt < 2; ++mt) {
        int nn[4];
#pragma unroll
        for (int r = 0; r < 4; ++r)
            nn[r] = nodeBase + mt * 16 + q * 4 + r;
#pragma unroll
        for (int nt = 0; nt < 8; ++nt) {
            int col = nt * 16 + m16;
            float bb = b2s[col];
#pragma unroll
            for (int r = 0; r < 4; ++r) {
                if (nn[r] < N_NODES) {
                    float v = acc[mt][nt][r] + cc[mt][r] * bb;
                    out[(size_t)nn[r] * OUT_CH + col] = v > 0.0f ? v : 0.0f;
                }
            }
        }
    }
}

extern "C" void kernel_launch(void* const* d_in, const int* in_sizes, int n_in,
                              void* d_out, int out_size, void* d_ws, size_t ws_size,
                              hipStream_t stream) {
    const float* x  = (const float*)d_in[0];
    const int*   ei = (const int*)d_in[1];
    const float* ea = (const float*)d_in[2];
    const float* W1 = (const float*)d_in[3];
    const float* b1 = (const float*)d_in[4];
    const float* W2 = (const float*)d_in[5];
    const float* b2 = (const float*)d_in[6];
    float* out = (float*)d_out;

    char* wsb = (char*)d_ws;
    unsigned int*   hsum   = (unsigned int*)  (wsb + OFF_HSUM);
    _Float16*       z      = (_Float16*)      (wsb + OFF_Z);
    float4*         crec   = (float4*)        (wsb + OFF_CREC);
    float*          cnt    = (float*)         (wsb + OFF_CNT);
    unsigned char*  ntype  = (unsigned char*) (wsb + OFF_NTYPE);
    unsigned*       curs   = (unsigned*)      (wsb + OFF_CURS);

    // zero hsum/cnt/padded-cursors
    gnn_prep0<<<(825000 + 4096 + 255) / 256, 256, 0, stream>>>(
        (uint4*)hsum, (float4*)cnt, (uint4*)curs);

    // node-level W1 pre-GEMM (reads x f32 directly) + ntype side effect
    gnn_zgemm<<<(N_NODES + 127) / 128, 256, 0, stream>>>(x, W1, z, ntype);

    // masked-edge compaction: line-padded sharded cursors (r11 false-sharing fix)
    gnn_compact<<<N_EDGES / 256, 256, 0, stream>>>(ei, ea, ntype, curs, crec, cnt);

    // edge phase: batched quad-per-edge gather + coalesced packed-f16 atomics
    gnn_edge_quad2<<<2048, 256, 0, stream>>>(crec, curs, z, W1, b1, hsum);

    // node-level layer 2 + relu via MFMA
    gnn_node_out<<<(N_NODES + 127) / 128, 256, 0, stream>>>(
        (const _Float16*)hsum, cnt, W2, b2, out);
}